// Round 4
// baseline (622.298 us; speedup 1.0000x reference)
//
#include <hip/hip_runtime.h>
#include <hip/hip_bf16.h>

// Problem constants (fixed by the reference)
#define NN 100000
#define EE 1600000
#define NODE_DIM 128
#define HID 64
#define NGRAPH 256
#define BN_EPS 1e-5f
#define NSLICE 8
#define SLICE_N 12500        // NN / NSLICE

struct bf16x4 { __hip_bfloat16 x, y, z, w; };   // 8-byte packed store

// ---------------- workspace layout (units of 4 bytes) ----------------
#define I_DEG   0                         // int[NN]
#define I_OFF   100032                    // int[NN+1]
#define I_CUR   200064                    // int[NN]
#define I_BS    300096                    // int[128]
#define I_BO    300224                    // int[128]
#define I_SRC   300352                    // int[EE]
#define I_DINV  1900352                   // float[NN]
#define I_WC    2000352                   // float[128*64 + 64]
#define I_BUFA  2008608                   // bf16[NN*64] (uses half the region)
#define I_BUFB  8408608                   // float[NN*64]
#define I_SUMS  14808608                  // float[NGRAPH*HID]

// ---------------- graph prep ----------------

__global__ void count_k(const int* __restrict__ dst, int* __restrict__ cnt) {
    int e = blockIdx.x * 256 + threadIdx.x;   // grid exactly EE
    int d = __builtin_nontemporal_load(dst + e);
    atomicAdd(&cnt[d], 1);
}

__global__ void dinv_k(const int* __restrict__ cnt, float* __restrict__ dinv, int n) {
    int i = blockIdx.x * 256 + threadIdx.x;
    if (i < n) dinv[i] = rsqrtf((float)(cnt[i] + 1));   // +1 self loop
}

// exclusive scan, stage 1: per-block (1024 elements) partial scan + block sums
__global__ void scan1_k(const int* __restrict__ in, int* __restrict__ part,
                        int* __restrict__ bsums, int n) {
    __shared__ int wsum[4];
    __shared__ int woff[4];
    int t = threadIdx.x;
    int base = blockIdx.x * 1024 + t * 4;
    int v0 = 0, v1 = 0, v2 = 0, v3 = 0;
    if (base + 3 < n) {
        v0 = in[base]; v1 = in[base + 1]; v2 = in[base + 2]; v3 = in[base + 3];
    } else {
        if (base     < n) v0 = in[base];
        if (base + 1 < n) v1 = in[base + 1];
        if (base + 2 < n) v2 = in[base + 2];
    }
    int s = v0 + v1 + v2 + v3;
    int lane = t & 63, wid = t >> 6;
    int x = s;
    #pragma unroll
    for (int d = 1; d < 64; d <<= 1) {
        int y = __shfl_up(x, d, 64);
        if (lane >= d) x += y;
    }
    if (lane == 63) wsum[wid] = x;
    __syncthreads();
    if (t == 0) {
        int r = 0;
        for (int w = 0; w < 4; ++w) { woff[w] = r; r += wsum[w]; }
        bsums[blockIdx.x] = r;
    }
    __syncthreads();
    int ex = woff[wid] + (x - s);
    if (base     < n) part[base]     = ex;
    if (base + 1 < n) part[base + 1] = ex + v0;
    if (base + 2 < n) part[base + 2] = ex + v0 + v1;
    if (base + 3 < n) part[base + 3] = ex + v0 + v1 + v2;
}

// stage 2: scan the (<=128) block sums with one block of 128 threads
__global__ void scan2_k(const int* __restrict__ bsums, int* __restrict__ boffs, int nb) {
    __shared__ int wsum[2];
    __shared__ int woff2[2];
    int t = threadIdx.x;
    int v = (t < nb) ? bsums[t] : 0;
    int lane = t & 63, wid = t >> 6;
    int x = v;
    #pragma unroll
    for (int d = 1; d < 64; d <<= 1) {
        int y = __shfl_up(x, d, 64);
        if (lane >= d) x += y;
    }
    if (lane == 63) wsum[wid] = x;
    __syncthreads();
    if (t == 0) { woff2[0] = 0; woff2[1] = wsum[0]; }
    __syncthreads();
    int ex = woff2[wid] + (x - v);
    if (t < nb) boffs[t] = ex;
}

// stage 3: add block offsets in place; init cursor; write off[N]
__global__ void scan3_k(int* __restrict__ off, const int* __restrict__ boffs,
                        int* __restrict__ cursor, int n, int total) {
    int i = blockIdx.x * 256 + threadIdx.x;
    if (i < n) {
        int v = off[i] + boffs[i >> 10];
        off[i] = v;
        cursor[i] = v;
    }
    if (i == 0) off[n] = total;
}

// XCD-sliced CSR fill. Non-temporal streaming reads keep the dirty csrc
// lines resident in each XCD's L2 (evict-first on the 7 MB dst/src stream),
// killing the RMW refetch + writeback amplification.
__global__ __launch_bounds__(256) void fill_k(const int* __restrict__ srcA,
                                              const int* __restrict__ dstA,
                                              int* __restrict__ cursor,
                                              int* __restrict__ csrc) {
    int slice = blockIdx.x & 7;
    int chunk = blockIdx.x >> 3;
    int lo = slice * SLICE_N;
    int hi = lo + SLICE_N;
    int base = chunk * 2048 + threadIdx.x;
    #pragma unroll
    for (int j = 0; j < 8; ++j) {
        int e = base + j * 256;
        if (e < EE) {
            int d = __builtin_nontemporal_load(dstA + e);
            if (d >= lo && d < hi) {
                int s = __builtin_nontemporal_load(srcA + e);
                int pos = atomicAdd(&cursor[d], 1);
                csrc[pos] = s;
            }
        }
    }
}

// ---------------- fused input-proj weight: Wc = W_in @ conv_W0, bc = b_in @ conv_W0 ----------------
__global__ void wc_k(const float* __restrict__ Win, const float* __restrict__ bin,
                     const float* __restrict__ cw0, float* __restrict__ Wc) {
    int idx = blockIdx.x * 256 + threadIdx.x;
    if (idx < NODE_DIM * HID) {
        int k = idx >> 6, c = idx & 63;
        float a = 0.f;
        #pragma unroll 8
        for (int j = 0; j < HID; ++j) a += Win[k * HID + j] * cw0[j * HID + c];
        Wc[idx] = a;
    } else if (idx < NODE_DIM * HID + HID) {
        int c = idx - NODE_DIM * HID;
        float a = 0.f;
        #pragma unroll 8
        for (int j = 0; j < HID; ++j) a += bin[j] * cw0[j * HID + c];
        Wc[idx] = a;
    }
}

// ---------------- transform GEMM: out[n,64] = bf16(in[n,K] @ W[K,64] (+bias)) ----------------
// 64x64 tile per 256-thread block; 4x4 register tile per thread; A/B staged
// in LDS in 64-k chunks; all LDS traffic is ds_read_b128 / ds_write_b128.
template <int K, bool BIAS>
__global__ __launch_bounds__(256) void gemm_k(const float* __restrict__ in,
                                              const float* __restrict__ Wg,
                                              const float* __restrict__ bias,
                                              __hip_bfloat16* __restrict__ out) {
    __shared__ float As[64][68];    // +4 pad keeps 16B alignment, breaks bank aliasing
    __shared__ float Bs[64][64];
    int t = threadIdx.x;
    int tx = t & 15, ty = t >> 4;
    int rowBase = blockIdx.x * 64;
    float acc[4][4] = {};

    for (int kc = 0; kc < K; kc += 64) {
        #pragma unroll
        for (int p = 0; p < 4; ++p) {
            int q = t + p * 256;            // 0..1023
            int r = q >> 4, kk = (q & 15) * 4;
            int row = rowBase + r;
            float4 v = make_float4(0.f, 0.f, 0.f, 0.f);
            if (row < NN) v = *(const float4*)(&in[(long)row * K + kc + kk]);
            *(float4*)(&As[r][kk]) = v;
        }
        #pragma unroll
        for (int p = 0; p < 4; ++p) {
            int q = t + p * 256;
            int k = q >> 4, cc = (q & 15) * 4;
            *(float4*)(&Bs[k][cc]) = *(const float4*)(&Wg[(kc + k) * 64 + cc]);
        }
        __syncthreads();
        #pragma unroll
        for (int k0 = 0; k0 < 64; k0 += 4) {
            float4 A0 = *(const float4*)(&As[ty * 4 + 0][k0]);
            float4 A1 = *(const float4*)(&As[ty * 4 + 1][k0]);
            float4 A2 = *(const float4*)(&As[ty * 4 + 2][k0]);
            float4 A3 = *(const float4*)(&As[ty * 4 + 3][k0]);
            float4 B0 = *(const float4*)(&Bs[k0 + 0][tx * 4]);
            float4 B1 = *(const float4*)(&Bs[k0 + 1][tx * 4]);
            float4 B2 = *(const float4*)(&Bs[k0 + 2][tx * 4]);
            float4 B3 = *(const float4*)(&Bs[k0 + 3][tx * 4]);
            #define ROWSTEP(Ai, i) \
                acc[i][0] += Ai.x * B0.x + Ai.y * B1.x + Ai.z * B2.x + Ai.w * B3.x; \
                acc[i][1] += Ai.x * B0.y + Ai.y * B1.y + Ai.z * B2.y + Ai.w * B3.y; \
                acc[i][2] += Ai.x * B0.z + Ai.y * B1.z + Ai.z * B2.z + Ai.w * B3.z; \
                acc[i][3] += Ai.x * B0.w + Ai.y * B1.w + Ai.z * B2.w + Ai.w * B3.w;
            ROWSTEP(A0, 0) ROWSTEP(A1, 1) ROWSTEP(A2, 2) ROWSTEP(A3, 3)
            #undef ROWSTEP
        }
        __syncthreads();
    }

    int c0 = tx * 4;
    float b0 = 0.f, b1 = 0.f, b2 = 0.f, b3 = 0.f;
    if (BIAS) { b0 = bias[c0]; b1 = bias[c0 + 1]; b2 = bias[c0 + 2]; b3 = bias[c0 + 3]; }
    #pragma unroll
    for (int i = 0; i < 4; ++i) {
        int row = rowBase + ty * 4 + i;
        if (row < NN) {
            bf16x4 v;
            v.x = __float2bfloat16(acc[i][0] + b0);
            v.y = __float2bfloat16(acc[i][1] + b1);
            v.z = __float2bfloat16(acc[i][2] + b2);
            v.w = __float2bfloat16(acc[i][3] + b3);
            *(bf16x4*)(&out[(long)row * HID + c0]) = v;
        }
    }
}

// ---------------- aggregate: out[i] = relu(BN(selfloop + sum_edges + conv_b)) ----------------
// one wave per node, lane = channel; hw gathered as bf16 (half the bytes);
// weight recomputed from dinv; edge loop unrolled x4 for MLP.
__global__ __launch_bounds__(256) void aggregate_k(const __hip_bfloat16* __restrict__ hw,
                                                   const int* __restrict__ off,
                                                   const int* __restrict__ src,
                                                   const float* __restrict__ dinv,
                                                   const float* __restrict__ convb,
                                                   const float* __restrict__ gamma,
                                                   const float* __restrict__ beta,
                                                   const float* __restrict__ mean,
                                                   const float* __restrict__ var,
                                                   float* __restrict__ out) {
    int lane = threadIdx.x & 63;
    int i = __builtin_amdgcn_readfirstlane((int)blockIdx.x * 4 + (threadIdx.x >> 6));
    float sc = gamma[lane] * rsqrtf(var[lane] + BN_EPS);
    float sh = (convb[lane] - mean[lane]) * sc + beta[lane];
    float di = dinv[i];
    float acc0 = __bfloat162float(hw[(long)i * HID + lane]) * di * di;  // self loop
    float acc1 = 0.f, acc2 = 0.f, acc3 = 0.f;
    int e0 = off[i], e1 = off[i + 1];
    int e = e0;
    for (; e + 4 <= e1; e += 4) {
        int s0 = src[e], s1 = src[e + 1], s2 = src[e + 2], s3 = src[e + 3];
        float w0 = dinv[s0], w1 = dinv[s1], w2 = dinv[s2], w3 = dinv[s3];
        float h0 = __bfloat162float(hw[(long)s0 * HID + lane]);
        float h1 = __bfloat162float(hw[(long)s1 * HID + lane]);
        float h2 = __bfloat162float(hw[(long)s2 * HID + lane]);
        float h3 = __bfloat162float(hw[(long)s3 * HID + lane]);
        acc0 += h0 * (w0 * di);
        acc1 += h1 * (w1 * di);
        acc2 += h2 * (w2 * di);
        acc3 += h3 * (w3 * di);
    }
    for (; e < e1; ++e) {
        int s = src[e];
        acc0 += __bfloat162float(hw[(long)s * HID + lane]) * (dinv[s] * di);
    }
    float acc = (acc0 + acc1) + (acc2 + acc3);
    float val = fmaxf(acc * sc + sh, 0.f);
    out[(long)i * HID + lane] = val;
}

// ---------------- pooling stage 1: parallel segmented sum over sorted batch ----------------
__global__ __launch_bounds__(256) void pool1_k(const float* __restrict__ h,
                                               const int* __restrict__ batch,
                                               float* __restrict__ sums) {
    int lane = threadIdx.x & 63;
    int wid = threadIdx.x >> 6;
    int chunk = blockIdx.x * 4 + wid;
    int i0 = chunk * 64;
    if (i0 >= NN) return;
    int i1 = i0 + 64;
    if (i1 > NN) i1 = NN;
    int g = batch[i0];
    float acc = 0.f;
    for (int i = i0; i < i1; ++i) {
        int bi = batch[i];
        if (bi != g) {
            atomicAdd(&sums[g * HID + lane], acc);
            acc = 0.f;
            g = bi;
        }
        acc += h[(long)i * HID + lane];
    }
    atomicAdd(&sums[g * HID + lane], acc);
}

// ---------------- pooling stage 2 + 3-layer MLP, one block per graph ----------------
__device__ __forceinline__ int lower_bound_i(const int* __restrict__ a, int n, int key) {
    int lo = 0, hi = n;
    while (lo < hi) {
        int m = (lo + hi) >> 1;
        if (a[m] < key) lo = m + 1; else hi = m;
    }
    return lo;
}

__global__ __launch_bounds__(64) void mlp_k(const float* __restrict__ sums,
                                            const int* __restrict__ batch,
                                            const float* __restrict__ W1, const float* __restrict__ b1,
                                            const float* __restrict__ W2, const float* __restrict__ b2,
                                            const float* __restrict__ W3, const float* __restrict__ b3,
                                            float* __restrict__ out) {
    int g = blockIdx.x;
    int lane = threadIdx.x;
    int start = lower_bound_i(batch, NN, g);
    int end = lower_bound_i(batch, NN, g + 1);
    float cnt = (float)(end - start);
    float gv = sums[g * HID + lane] / fmaxf(cnt, 1.0f);

    __shared__ float gs[HID];
    __shared__ float h1s[HID];
    gs[lane] = gv;
    __syncthreads();

    float a1 = b1[lane];
    #pragma unroll 8
    for (int k = 0; k < HID; ++k) a1 += gs[k] * W1[k * HID + lane];
    a1 = fmaxf(a1, 0.f);
    h1s[lane] = a1;
    __syncthreads();

    float a2 = 0.f;
    if (lane < 32) {
        a2 = b2[lane];
        #pragma unroll 8
        for (int k = 0; k < HID; ++k) a2 += h1s[k] * W2[k * 32 + lane];
        a2 = fmaxf(a2, 0.f);
    }
    float p = (lane < 32) ? a2 * W3[lane] : 0.f;
    #pragma unroll
    for (int d = 32; d >= 1; d >>= 1) p += __shfl_down(p, d, 64);
    if (lane == 0) out[g] = p + b3[0];
}

// ---------------- host launch ----------------
extern "C" void kernel_launch(void* const* d_in, const int* in_sizes, int n_in,
                              void* d_out, int out_size, void* d_ws, size_t ws_size,
                              hipStream_t stream) {
    (void)in_sizes; (void)n_in; (void)out_size; (void)ws_size;

    const float* x      = (const float*)d_in[0];
    const int*   eidx   = (const int*)d_in[1];      // [2,E]: src then dst
    const int*   batch  = (const int*)d_in[2];
    const float* W_in   = (const float*)d_in[3];
    const float* b_in   = (const float*)d_in[4];
    const float* conv_W = (const float*)d_in[5];    // [3,64,64]
    const float* conv_b = (const float*)d_in[6];    // [3,64]
    const float* gamma  = (const float*)d_in[7];
    const float* beta   = (const float*)d_in[8];
    const float* mean   = (const float*)d_in[9];
    const float* var    = (const float*)d_in[10];
    const float* W1     = (const float*)d_in[11];
    const float* b1     = (const float*)d_in[12];
    const float* W2     = (const float*)d_in[13];
    const float* b2     = (const float*)d_in[14];
    const float* W3     = (const float*)d_in[15];
    const float* b3     = (const float*)d_in[16];
    float* outp = (float*)d_out;

    int*   wsi = (int*)d_ws;
    float* wsf = (float*)d_ws;

    int*   deg    = wsi + I_DEG;
    int*   off    = wsi + I_OFF;
    int*   cur    = wsi + I_CUR;
    int*   bsums  = wsi + I_BS;
    int*   boffs  = wsi + I_BO;
    int*   csrc   = wsi + I_SRC;
    float* dinv   = wsf + I_DINV;
    float* Wc     = wsf + I_WC;
    __hip_bfloat16* bufA = (__hip_bfloat16*)(wsf + I_BUFA);
    float* bufB   = wsf + I_BUFB;
    float* sums   = wsf + I_SUMS;

    const int* esrc = eidx;
    const int* edst = eidx + EE;

    hipMemsetAsync(deg, 0, NN * sizeof(int), stream);
    hipMemsetAsync(sums, 0, NGRAPH * HID * sizeof(float), stream);

    count_k<<<EE / 256, 256, 0, stream>>>(edst, deg);
    dinv_k<<<(NN + 255) / 256, 256, 0, stream>>>(deg, dinv, NN);

    int nb = (NN + 1023) / 1024;   // 98
    scan1_k<<<nb, 256, 0, stream>>>(deg, off, bsums, NN);
    scan2_k<<<1, 128, 0, stream>>>(bsums, boffs, nb);
    scan3_k<<<(NN + 255) / 256, 256, 0, stream>>>(off, boffs, cur, NN, EE);

    wc_k<<<(NODE_DIM * HID + HID + 255) / 256, 256, 0, stream>>>(W_in, b_in, conv_W, Wc);

    int nchunk = (EE + 2047) / 2048;            // 782
    fill_k<<<nchunk * NSLICE, 256, 0, stream>>>(esrc, edst, cur, csrc);

    int ngemm = (NN + 63) / 64;                 // 1563
    // layer 0: fused input projection + conv transform
    gemm_k<NODE_DIM, true><<<ngemm, 256, 0, stream>>>(x, Wc, Wc + NODE_DIM * HID, bufA);
    aggregate_k<<<NN / 4, 256, 0, stream>>>(bufA, off, csrc, dinv,
                                            conv_b + 0 * HID, gamma + 0 * HID, beta + 0 * HID,
                                            mean + 0 * HID, var + 0 * HID, bufB);
    // layer 1
    gemm_k<HID, false><<<ngemm, 256, 0, stream>>>(bufB, conv_W + 1 * HID * HID, nullptr, bufA);
    aggregate_k<<<NN / 4, 256, 0, stream>>>(bufA, off, csrc, dinv,
                                            conv_b + 1 * HID, gamma + 1 * HID, beta + 1 * HID,
                                            mean + 1 * HID, var + 1 * HID, bufB);
    // layer 2
    gemm_k<HID, false><<<ngemm, 256, 0, stream>>>(bufB, conv_W + 2 * HID * HID, nullptr, bufA);
    aggregate_k<<<NN / 4, 256, 0, stream>>>(bufA, off, csrc, dinv,
                                            conv_b + 2 * HID, gamma + 2 * HID, beta + 2 * HID,
                                            mean + 2 * HID, var + 2 * HID, bufB);

    // mean pool (parallel) + MLP
    pool1_k<<<(NN / 64 + 3) / 4, 256, 0, stream>>>(bufB, batch, sums);
    mlp_k<<<NGRAPH, 64, 0, stream>>>(sums, batch, W1, b1, W2, b2, W3, b3, outp);
}

// Round 5
// 529.083 us; speedup vs baseline: 1.1762x; 1.1762x over previous
//
#include <hip/hip_runtime.h>
#include <hip/hip_bf16.h>

// Problem constants (fixed by the reference)
#define NN 100000
#define EE 1600000
#define NODE_DIM 128
#define HID 64
#define NGRAPH 256
#define BN_EPS 1e-5f

// counting-sort geometry
#define NB 196            // coarse buckets: dst>>9  (99999>>9 == 195)
#define BW 512            // bucket width (power of 2)
#define CH 4096           // edges per chunk
#define NCHUNK 391        // ceil(EE/CH)
#define MHIST (NB * NCHUNK)   // 76636
#define MAXB 12288        // LDS capacity per bucket (avg 8192, sigma ~90)

struct bf16x4 { __hip_bfloat16 x, y, z, w; };   // 8-byte packed store

// ---------------- workspace layout (units of 4 bytes) ----------------
#define I_OFF   0                 // int[NN+1]
#define I_DEG   100032            // int[NN]
#define I_HIST  200064            // int[MHIST]
#define I_HS    276864            // int[MHIST] (scanned)
#define I_BS    353664            // int[128]
#define I_BO    353792            // int[128]
#define I_PAIR  353920            // int2[EE]  (3,200,000 words)
#define I_SRCS  3553920           // int[EE]   sorted csrc
#define I_DINV  5153920           // float[NN]
#define I_WC    5253952           // float[128*64 + 64]
#define I_BUFA  5262208           // bf16[NN*64] (3,200,000 words)
#define I_BUFB  8462208           // float[NN*64]
#define I_SUMS  14862208          // float[NGRAPH*HID]
// end = 14,878,592 words = 59.5 MB

// ---------------- pass A: per-chunk coarse histogram ----------------
__global__ __launch_bounds__(256) void hist_k(const int* __restrict__ dst,
                                              int* __restrict__ hist) {
    __shared__ int h[NB];
    for (int i = threadIdx.x; i < NB; i += 256) h[i] = 0;
    __syncthreads();
    int base = blockIdx.x * CH + threadIdx.x;
    #pragma unroll
    for (int j = 0; j < 16; ++j) {
        int e = base + j * 256;
        if (e < EE) {
            int d = __builtin_nontemporal_load(dst + e);
            atomicAdd(&h[d >> 9], 1);
        }
    }
    __syncthreads();
    for (int i = threadIdx.x; i < NB; i += 256)
        hist[i * NCHUNK + blockIdx.x] = h[i];   // bucket-major for the scan
}

// ---------------- generic exclusive scan (3 stages) ----------------
__global__ void scan1_k(const int* __restrict__ in, int* __restrict__ part,
                        int* __restrict__ bsums, int n) {
    __shared__ int wsum[4];
    __shared__ int woff[4];
    int t = threadIdx.x;
    int base = blockIdx.x * 1024 + t * 4;
    int v0 = 0, v1 = 0, v2 = 0, v3 = 0;
    if (base + 3 < n) {
        v0 = in[base]; v1 = in[base + 1]; v2 = in[base + 2]; v3 = in[base + 3];
    } else {
        if (base     < n) v0 = in[base];
        if (base + 1 < n) v1 = in[base + 1];
        if (base + 2 < n) v2 = in[base + 2];
    }
    int s = v0 + v1 + v2 + v3;
    int lane = t & 63, wid = t >> 6;
    int x = s;
    #pragma unroll
    for (int d = 1; d < 64; d <<= 1) {
        int y = __shfl_up(x, d, 64);
        if (lane >= d) x += y;
    }
    if (lane == 63) wsum[wid] = x;
    __syncthreads();
    if (t == 0) {
        int r = 0;
        for (int w = 0; w < 4; ++w) { woff[w] = r; r += wsum[w]; }
        bsums[blockIdx.x] = r;
    }
    __syncthreads();
    int ex = woff[wid] + (x - s);
    if (base     < n) part[base]     = ex;
    if (base + 1 < n) part[base + 1] = ex + v0;
    if (base + 2 < n) part[base + 2] = ex + v0 + v1;
    if (base + 3 < n) part[base + 3] = ex + v0 + v1 + v2;
}

__global__ void scan2_k(const int* __restrict__ bsums, int* __restrict__ boffs, int nb) {
    __shared__ int wsum[2];
    __shared__ int woff2[2];
    int t = threadIdx.x;
    int v = (t < nb) ? bsums[t] : 0;
    int lane = t & 63, wid = t >> 6;
    int x = v;
    #pragma unroll
    for (int d = 1; d < 64; d <<= 1) {
        int y = __shfl_up(x, d, 64);
        if (lane >= d) x += y;
    }
    if (lane == 63) wsum[wid] = x;
    __syncthreads();
    if (t == 0) { woff2[0] = 0; woff2[1] = wsum[0]; }
    __syncthreads();
    int ex = woff2[wid] + (x - v);
    if (t < nb) boffs[t] = ex;
}

__global__ void scan3g_k(int* __restrict__ arr, const int* __restrict__ boffs, int n) {
    int i = blockIdx.x * 256 + threadIdx.x;
    if (i < n) arr[i] += boffs[i >> 10];
}

// ---------------- pass B: coarse placement (dst,src) pairs by bucket ----------------
__global__ __launch_bounds__(256) void sortB_k(const int* __restrict__ srcA,
                                               const int* __restrict__ dstA,
                                               const int* __restrict__ hs,
                                               int2* __restrict__ pair) {
    __shared__ int lcur[NB];
    for (int i = threadIdx.x; i < NB; i += 256)
        lcur[i] = hs[i * NCHUNK + blockIdx.x];
    __syncthreads();
    int base = blockIdx.x * CH + threadIdx.x;
    #pragma unroll
    for (int j = 0; j < 16; ++j) {
        int e = base + j * 256;
        if (e < EE) {
            int d = __builtin_nontemporal_load(dstA + e);
            int s = __builtin_nontemporal_load(srcA + e);
            int pos = atomicAdd(&lcur[d >> 9], 1);
            pair[pos] = make_int2(d, s);
        }
    }
}

// ---------------- pass C: per-bucket exact sort in LDS; emits deg/off/csrc ----------------
__global__ __launch_bounds__(256) void fineC_k(const int2* __restrict__ pair,
                                               const int* __restrict__ hs,
                                               int* __restrict__ deg,
                                               int* __restrict__ off,
                                               int* __restrict__ csrc) {
    __shared__ int cnt[BW];
    __shared__ int loff[BW];
    __shared__ int wsum[4];
    __shared__ int woff[4];
    __shared__ int ssrc[MAXB];
    int b = blockIdx.x;
    int t = threadIdx.x;
    int base = hs[b * NCHUNK];
    int end  = (b == NB - 1) ? EE : hs[(b + 1) * NCHUNK];
    int m = end - base;

    for (int i = t; i < BW; i += 256) cnt[i] = 0;
    __syncthreads();
    for (int i = t; i < m; i += 256) {
        int2 p = pair[base + i];
        atomicAdd(&cnt[p.x & (BW - 1)], 1);
    }
    __syncthreads();

    // block exclusive scan of cnt[512]: 2 elements per thread
    int c0 = cnt[2 * t], c1 = cnt[2 * t + 1];
    int s = c0 + c1;
    int lane = t & 63, wid = t >> 6;
    int x = s;
    #pragma unroll
    for (int d = 1; d < 64; d <<= 1) {
        int y = __shfl_up(x, d, 64);
        if (lane >= d) x += y;
    }
    if (lane == 63) wsum[wid] = x;
    __syncthreads();
    if (t == 0) {
        int r = 0;
        for (int w = 0; w < 4; ++w) { woff[w] = r; r += wsum[w]; }
    }
    __syncthreads();
    int ex = woff[wid] + (x - s);
    loff[2 * t] = ex;
    loff[2 * t + 1] = ex + c0;
    __syncthreads();

    // node-level outputs (deg, off)
    int node0 = b << 9;
    for (int i = t; i < BW; i += 256) {
        int node = node0 + i;
        if (node < NN) { deg[node] = cnt[i]; off[node] = base + loff[i]; }
        else if (node == NN) { off[NN] = EE; }
    }
    __syncthreads();

    // reuse cnt[] as placement cursors
    for (int i = t; i < BW; i += 256) cnt[i] = loff[i];
    __syncthreads();
    for (int i = t; i < m; i += 256) {
        int2 p = pair[base + i];
        int pos = atomicAdd(&cnt[p.x & (BW - 1)], 1);
        if (pos < MAXB) ssrc[pos] = p.y;
        else            csrc[base + pos] = p.y;   // never taken statistically
    }
    __syncthreads();
    int mm = m < MAXB ? m : MAXB;
    for (int i = t; i < mm; i += 256) csrc[base + i] = ssrc[i];   // coalesced
}

__global__ void dinv_k(const int* __restrict__ cnt, float* __restrict__ dinv, int n) {
    int i = blockIdx.x * 256 + threadIdx.x;
    if (i < n) dinv[i] = rsqrtf((float)(cnt[i] + 1));   // +1 self loop
}

// ---------------- fused input-proj weight: Wc = W_in @ conv_W0, bc = b_in @ conv_W0 ----------------
__global__ void wc_k(const float* __restrict__ Win, const float* __restrict__ bin,
                     const float* __restrict__ cw0, float* __restrict__ Wc) {
    int idx = blockIdx.x * 256 + threadIdx.x;
    if (idx < NODE_DIM * HID) {
        int k = idx >> 6, c = idx & 63;
        float a = 0.f;
        #pragma unroll 8
        for (int j = 0; j < HID; ++j) a += Win[k * HID + j] * cw0[j * HID + c];
        Wc[idx] = a;
    } else if (idx < NODE_DIM * HID + HID) {
        int c = idx - NODE_DIM * HID;
        float a = 0.f;
        #pragma unroll 8
        for (int j = 0; j < HID; ++j) a += bin[j] * cw0[j * HID + c];
        Wc[idx] = a;
    }
}

// ---------------- transform GEMM: out[n,64] = bf16(in[n,K] @ W[K,64] (+bias)) ----------------
template <int K, bool BIAS>
__global__ __launch_bounds__(256) void gemm_k(const float* __restrict__ in,
                                              const float* __restrict__ Wg,
                                              const float* __restrict__ bias,
                                              __hip_bfloat16* __restrict__ out) {
    __shared__ float As[64][68];
    __shared__ float Bs[64][64];
    int t = threadIdx.x;
    int tx = t & 15, ty = t >> 4;
    int rowBase = blockIdx.x * 64;
    float acc[4][4] = {};

    for (int kc = 0; kc < K; kc += 64) {
        #pragma unroll
        for (int p = 0; p < 4; ++p) {
            int q = t + p * 256;
            int r = q >> 4, kk = (q & 15) * 4;
            int row = rowBase + r;
            float4 v = make_float4(0.f, 0.f, 0.f, 0.f);
            if (row < NN) v = *(const float4*)(&in[(long)row * K + kc + kk]);
            *(float4*)(&As[r][kk]) = v;
        }
        #pragma unroll
        for (int p = 0; p < 4; ++p) {
            int q = t + p * 256;
            int k = q >> 4, cc = (q & 15) * 4;
            *(float4*)(&Bs[k][cc]) = *(const float4*)(&Wg[(kc + k) * 64 + cc]);
        }
        __syncthreads();
        #pragma unroll
        for (int k0 = 0; k0 < 64; k0 += 4) {
            float4 A0 = *(const float4*)(&As[ty * 4 + 0][k0]);
            float4 A1 = *(const float4*)(&As[ty * 4 + 1][k0]);
            float4 A2 = *(const float4*)(&As[ty * 4 + 2][k0]);
            float4 A3 = *(const float4*)(&As[ty * 4 + 3][k0]);
            float4 B0 = *(const float4*)(&Bs[k0 + 0][tx * 4]);
            float4 B1 = *(const float4*)(&Bs[k0 + 1][tx * 4]);
            float4 B2 = *(const float4*)(&Bs[k0 + 2][tx * 4]);
            float4 B3 = *(const float4*)(&Bs[k0 + 3][tx * 4]);
            #define ROWSTEP(Ai, i) \
                acc[i][0] += Ai.x * B0.x + Ai.y * B1.x + Ai.z * B2.x + Ai.w * B3.x; \
                acc[i][1] += Ai.x * B0.y + Ai.y * B1.y + Ai.z * B2.y + Ai.w * B3.y; \
                acc[i][2] += Ai.x * B0.z + Ai.y * B1.z + Ai.z * B2.z + Ai.w * B3.z; \
                acc[i][3] += Ai.x * B0.w + Ai.y * B1.w + Ai.z * B2.w + Ai.w * B3.w;
            ROWSTEP(A0, 0) ROWSTEP(A1, 1) ROWSTEP(A2, 2) ROWSTEP(A3, 3)
            #undef ROWSTEP
        }
        __syncthreads();
    }

    int c0 = tx * 4;
    float b0 = 0.f, b1 = 0.f, b2 = 0.f, b3 = 0.f;
    if (BIAS) { b0 = bias[c0]; b1 = bias[c0 + 1]; b2 = bias[c0 + 2]; b3 = bias[c0 + 3]; }
    #pragma unroll
    for (int i = 0; i < 4; ++i) {
        int row = rowBase + ty * 4 + i;
        if (row < NN) {
            bf16x4 v;
            v.x = __float2bfloat16(acc[i][0] + b0);
            v.y = __float2bfloat16(acc[i][1] + b1);
            v.z = __float2bfloat16(acc[i][2] + b2);
            v.w = __float2bfloat16(acc[i][3] + b3);
            *(bf16x4*)(&out[(long)row * HID + c0]) = v;
        }
    }
}

// ---------------- aggregate: out[i] = relu(BN(selfloop + sum_edges + conv_b)) ----------------
__global__ __launch_bounds__(256) void aggregate_k(const __hip_bfloat16* __restrict__ hw,
                                                   const int* __restrict__ off,
                                                   const int* __restrict__ src,
                                                   const float* __restrict__ dinv,
                                                   const float* __restrict__ convb,
                                                   const float* __restrict__ gamma,
                                                   const float* __restrict__ beta,
                                                   const float* __restrict__ mean,
                                                   const float* __restrict__ var,
                                                   float* __restrict__ out) {
    int lane = threadIdx.x & 63;
    int i = __builtin_amdgcn_readfirstlane((int)blockIdx.x * 4 + (threadIdx.x >> 6));
    float sc = gamma[lane] * rsqrtf(var[lane] + BN_EPS);
    float sh = (convb[lane] - mean[lane]) * sc + beta[lane];
    float di = dinv[i];
    float acc0 = __bfloat162float(hw[(long)i * HID + lane]) * di * di;  // self loop
    float acc1 = 0.f, acc2 = 0.f, acc3 = 0.f;
    int e0 = off[i], e1 = off[i + 1];
    int e = e0;
    for (; e + 4 <= e1; e += 4) {
        int s0 = src[e], s1 = src[e + 1], s2 = src[e + 2], s3 = src[e + 3];
        float w0 = dinv[s0], w1 = dinv[s1], w2 = dinv[s2], w3 = dinv[s3];
        float h0 = __bfloat162float(hw[(long)s0 * HID + lane]);
        float h1 = __bfloat162float(hw[(long)s1 * HID + lane]);
        float h2 = __bfloat162float(hw[(long)s2 * HID + lane]);
        float h3 = __bfloat162float(hw[(long)s3 * HID + lane]);
        acc0 += h0 * (w0 * di);
        acc1 += h1 * (w1 * di);
        acc2 += h2 * (w2 * di);
        acc3 += h3 * (w3 * di);
    }
    for (; e < e1; ++e) {
        int s = src[e];
        acc0 += __bfloat162float(hw[(long)s * HID + lane]) * (dinv[s] * di);
    }
    float acc = (acc0 + acc1) + (acc2 + acc3);
    float val = fmaxf(acc * sc + sh, 0.f);
    out[(long)i * HID + lane] = val;
}

// ---------------- pooling stage 1: parallel segmented sum over sorted batch ----------------
__global__ __launch_bounds__(256) void pool1_k(const float* __restrict__ h,
                                               const int* __restrict__ batch,
                                               float* __restrict__ sums) {
    int lane = threadIdx.x & 63;
    int wid = threadIdx.x >> 6;
    int chunk = blockIdx.x * 4 + wid;
    int i0 = chunk * 64;
    if (i0 >= NN) return;
    int i1 = i0 + 64;
    if (i1 > NN) i1 = NN;
    int g = batch[i0];
    float acc = 0.f;
    for (int i = i0; i < i1; ++i) {
        int bi = batch[i];
        if (bi != g) {
            atomicAdd(&sums[g * HID + lane], acc);
            acc = 0.f;
            g = bi;
        }
        acc += h[(long)i * HID + lane];
    }
    atomicAdd(&sums[g * HID + lane], acc);
}

// ---------------- pooling stage 2 + 3-layer MLP, one block per graph ----------------
__device__ __forceinline__ int lower_bound_i(const int* __restrict__ a, int n, int key) {
    int lo = 0, hi = n;
    while (lo < hi) {
        int m = (lo + hi) >> 1;
        if (a[m] < key) lo = m + 1; else hi = m;
    }
    return lo;
}

__global__ __launch_bounds__(64) void mlp_k(const float* __restrict__ sums,
                                            const int* __restrict__ batch,
                                            const float* __restrict__ W1, const float* __restrict__ b1,
                                            const float* __restrict__ W2, const float* __restrict__ b2,
                                            const float* __restrict__ W3, const float* __restrict__ b3,
                                            float* __restrict__ out) {
    int g = blockIdx.x;
    int lane = threadIdx.x;
    int start = lower_bound_i(batch, NN, g);
    int end = lower_bound_i(batch, NN, g + 1);
    float cnt = (float)(end - start);
    float gv = sums[g * HID + lane] / fmaxf(cnt, 1.0f);

    __shared__ float gs[HID];
    __shared__ float h1s[HID];
    gs[lane] = gv;
    __syncthreads();

    float a1 = b1[lane];
    #pragma unroll 8
    for (int k = 0; k < HID; ++k) a1 += gs[k] * W1[k * HID + lane];
    a1 = fmaxf(a1, 0.f);
    h1s[lane] = a1;
    __syncthreads();

    float a2 = 0.f;
    if (lane < 32) {
        a2 = b2[lane];
        #pragma unroll 8
        for (int k = 0; k < HID; ++k) a2 += h1s[k] * W2[k * 32 + lane];
        a2 = fmaxf(a2, 0.f);
    }
    float p = (lane < 32) ? a2 * W3[lane] : 0.f;
    #pragma unroll
    for (int d = 32; d >= 1; d >>= 1) p += __shfl_down(p, d, 64);
    if (lane == 0) out[g] = p + b3[0];
}

// ---------------- host launch ----------------
extern "C" void kernel_launch(void* const* d_in, const int* in_sizes, int n_in,
                              void* d_out, int out_size, void* d_ws, size_t ws_size,
                              hipStream_t stream) {
    (void)in_sizes; (void)n_in; (void)out_size; (void)ws_size;

    const float* x      = (const float*)d_in[0];
    const int*   eidx   = (const int*)d_in[1];      // [2,E]: src then dst
    const int*   batch  = (const int*)d_in[2];
    const float* W_in   = (const float*)d_in[3];
    const float* b_in   = (const float*)d_in[4];
    const float* conv_W = (const float*)d_in[5];    // [3,64,64]
    const float* conv_b = (const float*)d_in[6];    // [3,64]
    const float* gamma  = (const float*)d_in[7];
    const float* beta   = (const float*)d_in[8];
    const float* mean   = (const float*)d_in[9];
    const float* var    = (const float*)d_in[10];
    const float* W1     = (const float*)d_in[11];
    const float* b1     = (const float*)d_in[12];
    const float* W2     = (const float*)d_in[13];
    const float* b2     = (const float*)d_in[14];
    const float* W3     = (const float*)d_in[15];
    const float* b3     = (const float*)d_in[16];
    float* outp = (float*)d_out;

    int*   wsi = (int*)d_ws;
    float* wsf = (float*)d_ws;

    int*   off    = wsi + I_OFF;
    int*   deg    = wsi + I_DEG;
    int*   hist   = wsi + I_HIST;
    int*   hs     = wsi + I_HS;
    int*   bsums  = wsi + I_BS;
    int*   boffs  = wsi + I_BO;
    int2*  pair   = (int2*)(wsi + I_PAIR);
    int*   csrc   = wsi + I_SRCS;
    float* dinv   = wsf + I_DINV;
    float* Wc     = wsf + I_WC;
    __hip_bfloat16* bufA = (__hip_bfloat16*)(wsf + I_BUFA);
    float* bufB   = wsf + I_BUFB;
    float* sums   = wsf + I_SUMS;

    const int* esrc = eidx;
    const int* edst = eidx + EE;

    hipMemsetAsync(sums, 0, NGRAPH * HID * sizeof(float), stream);

    // ---- graph prep: two-level counting sort -> deg, off, csrc (all coalesced writes)
    hist_k<<<NCHUNK, 256, 0, stream>>>(edst, hist);
    int nb1 = (MHIST + 1023) / 1024;                 // 75
    scan1_k<<<nb1, 256, 0, stream>>>(hist, hs, bsums, MHIST);
    scan2_k<<<1, 128, 0, stream>>>(bsums, boffs, nb1);
    scan3g_k<<<(MHIST + 255) / 256, 256, 0, stream>>>(hs, boffs, MHIST);
    wc_k<<<(NODE_DIM * HID + HID + 255) / 256, 256, 0, stream>>>(W_in, b_in, conv_W, Wc);
    sortB_k<<<NCHUNK, 256, 0, stream>>>(esrc, edst, hs, pair);
    fineC_k<<<NB, 256, 0, stream>>>(pair, hs, deg, off, csrc);
    dinv_k<<<(NN + 255) / 256, 256, 0, stream>>>(deg, dinv, NN);

    int ngemm = (NN + 63) / 64;                 // 1563
    // layer 0: fused input projection + conv transform
    gemm_k<NODE_DIM, true><<<ngemm, 256, 0, stream>>>(x, Wc, Wc + NODE_DIM * HID, bufA);
    aggregate_k<<<NN / 4, 256, 0, stream>>>(bufA, off, csrc, dinv,
                                            conv_b + 0 * HID, gamma + 0 * HID, beta + 0 * HID,
                                            mean + 0 * HID, var + 0 * HID, bufB);
    // layer 1
    gemm_k<HID, false><<<ngemm, 256, 0, stream>>>(bufB, conv_W + 1 * HID * HID, nullptr, bufA);
    aggregate_k<<<NN / 4, 256, 0, stream>>>(bufA, off, csrc, dinv,
                                            conv_b + 1 * HID, gamma + 1 * HID, beta + 1 * HID,
                                            mean + 1 * HID, var + 1 * HID, bufB);
    // layer 2
    gemm_k<HID, false><<<ngemm, 256, 0, stream>>>(bufB, conv_W + 2 * HID * HID, nullptr, bufA);
    aggregate_k<<<NN / 4, 256, 0, stream>>>(bufA, off, csrc, dinv,
                                            conv_b + 2 * HID, gamma + 2 * HID, beta + 2 * HID,
                                            mean + 2 * HID, var + 2 * HID, bufB);

    // mean pool (parallel) + MLP
    pool1_k<<<(NN / 64 + 3) / 4, 256, 0, stream>>>(bufB, batch, sums);
    mlp_k<<<NGRAPH, 64, 0, stream>>>(sums, batch, W1, b1, W2, b2, W3, b3, outp);
}

// Round 6
// 419.244 us; speedup vs baseline: 1.4843x; 1.2620x over previous
//
#include <hip/hip_runtime.h>
#include <hip/hip_bf16.h>

// Problem constants (fixed by the reference)
#define NN 100000
#define EE 1600000
#define NODE_DIM 128
#define HID 64
#define NGRAPH 256
#define BN_EPS 1e-5f

// counting-sort geometry
#define NB 196            // coarse buckets: dst>>9  (99999>>9 == 195)
#define BW 512            // bucket width (power of 2)
#define CH 4096           // edges per chunk
#define NCHUNK 391        // ceil(EE/CH)
#define MHIST (NB * NCHUNK)   // 76636
#define MAXB 12288        // LDS capacity per bucket (avg 8192)

typedef __attribute__((ext_vector_type(8))) short short8;   // 8 bf16 (4 VGPRs)
typedef __attribute__((ext_vector_type(4))) float f32x4;    // MFMA acc

// RNE float->bf16 (bit-exact, no API ambiguity)
static __device__ __forceinline__ short f2bf(float f) {
    unsigned u = __float_as_uint(f);
    unsigned r = (u + 0x7fffu + ((u >> 16) & 1u)) >> 16;
    return (short)r;
}

// ---------------- workspace layout (units of 4 bytes) ----------------
#define I_OFF   0                 // int[NN+1]
#define I_DEG   100032            // int[NN]
#define I_HIST  200064            // int[MHIST]
#define I_HS    276864            // int[MHIST] (scanned)
#define I_BS    353664            // int[128]
#define I_BO    353792            // int[128]
#define I_PAIR  353920            // int2[EE]  (3,200,000 words)
#define I_SRCS  3553920           // int[EE]   sorted csrc
#define I_DINV  5153920           // float[NN]
#define I_WC    5253952           // float[128*64 + 64]
#define I_WFA   5262208           // bf16[128*64]  (4096 words)
#define I_WF1   5266304           // bf16[64*64]   (2048 words)
#define I_WF2   5268352           // bf16[64*64]   (2048 words)
#define I_BUFA  5270400           // bf16[NN*64]  (3,200,000 words)
#define I_BUFB  8470400           // bf16[NN*64]  (3,200,000 words)
#define I_SUMS  11670400          // float[NGRAPH*HID]
// end = 11,686,784 words = 46.7 MB

// ---------------- pass A: per-chunk coarse histogram ----------------
__global__ __launch_bounds__(256) void hist_k(const int* __restrict__ dst,
                                              int* __restrict__ hist) {
    __shared__ int h[NB];
    for (int i = threadIdx.x; i < NB; i += 256) h[i] = 0;
    __syncthreads();
    int base = blockIdx.x * CH + threadIdx.x;
    #pragma unroll
    for (int j = 0; j < 16; ++j) {
        int e = base + j * 256;
        if (e < EE) {
            int d = __builtin_nontemporal_load(dst + e);
            atomicAdd(&h[d >> 9], 1);
        }
    }
    __syncthreads();
    for (int i = threadIdx.x; i < NB; i += 256)
        hist[i * NCHUNK + blockIdx.x] = h[i];   // bucket-major for the scan
}

// ---------------- generic exclusive scan (3 stages) ----------------
__global__ void scan1_k(const int* __restrict__ in, int* __restrict__ part,
                        int* __restrict__ bsums, int n) {
    __shared__ int wsum[4];
    __shared__ int woff[4];
    int t = threadIdx.x;
    int base = blockIdx.x * 1024 + t * 4;
    int v0 = 0, v1 = 0, v2 = 0, v3 = 0;
    if (base + 3 < n) {
        v0 = in[base]; v1 = in[base + 1]; v2 = in[base + 2]; v3 = in[base + 3];
    } else {
        if (base     < n) v0 = in[base];
        if (base + 1 < n) v1 = in[base + 1];
        if (base + 2 < n) v2 = in[base + 2];
    }
    int s = v0 + v1 + v2 + v3;
    int lane = t & 63, wid = t >> 6;
    int x = s;
    #pragma unroll
    for (int d = 1; d < 64; d <<= 1) {
        int y = __shfl_up(x, d, 64);
        if (lane >= d) x += y;
    }
    if (lane == 63) wsum[wid] = x;
    __syncthreads();
    if (t == 0) {
        int r = 0;
        for (int w = 0; w < 4; ++w) { woff[w] = r; r += wsum[w]; }
        bsums[blockIdx.x] = r;
    }
    __syncthreads();
    int ex = woff[wid] + (x - s);
    if (base     < n) part[base]     = ex;
    if (base + 1 < n) part[base + 1] = ex + v0;
    if (base + 2 < n) part[base + 2] = ex + v0 + v1;
    if (base + 3 < n) part[base + 3] = ex + v0 + v1 + v2;
}

__global__ void scan2_k(const int* __restrict__ bsums, int* __restrict__ boffs, int nb) {
    __shared__ int wsum[2];
    __shared__ int woff2[2];
    int t = threadIdx.x;
    int v = (t < nb) ? bsums[t] : 0;
    int lane = t & 63, wid = t >> 6;
    int x = v;
    #pragma unroll
    for (int d = 1; d < 64; d <<= 1) {
        int y = __shfl_up(x, d, 64);
        if (lane >= d) x += y;
    }
    if (lane == 63) wsum[wid] = x;
    __syncthreads();
    if (t == 0) { woff2[0] = 0; woff2[1] = wsum[0]; }
    __syncthreads();
    int ex = woff2[wid] + (x - v);
    if (t < nb) boffs[t] = ex;
}

__global__ void scan3g_k(int* __restrict__ arr, const int* __restrict__ boffs, int n) {
    int i = blockIdx.x * 256 + threadIdx.x;
    if (i < n) arr[i] += boffs[i >> 10];
}

// ---------------- pass B: coarse placement (dst,src) pairs by bucket ----------------
__global__ __launch_bounds__(256) void sortB_k(const int* __restrict__ srcA,
                                               const int* __restrict__ dstA,
                                               const int* __restrict__ hs,
                                               int2* __restrict__ pair) {
    __shared__ int lcur[NB];
    for (int i = threadIdx.x; i < NB; i += 256)
        lcur[i] = hs[i * NCHUNK + blockIdx.x];
    __syncthreads();
    int base = blockIdx.x * CH + threadIdx.x;
    #pragma unroll
    for (int j = 0; j < 16; ++j) {
        int e = base + j * 256;
        if (e < EE) {
            int d = __builtin_nontemporal_load(dstA + e);
            int s = __builtin_nontemporal_load(srcA + e);
            int pos = atomicAdd(&lcur[d >> 9], 1);
            pair[pos] = make_int2(d, s);
        }
    }
}

// ---------------- pass C: per-bucket exact sort in LDS; emits deg/off/csrc ----------------
__global__ __launch_bounds__(256) void fineC_k(const int2* __restrict__ pair,
                                               const int* __restrict__ hs,
                                               int* __restrict__ deg,
                                               int* __restrict__ off,
                                               int* __restrict__ csrc) {
    __shared__ int cnt[BW];
    __shared__ int loff[BW];
    __shared__ int wsum[4];
    __shared__ int woff[4];
    __shared__ int ssrc[MAXB];
    int b = blockIdx.x;
    int t = threadIdx.x;
    int base = hs[b * NCHUNK];
    int end  = (b == NB - 1) ? EE : hs[(b + 1) * NCHUNK];
    int m = end - base;

    for (int i = t; i < BW; i += 256) cnt[i] = 0;
    __syncthreads();
    for (int i = t; i < m; i += 256) {
        int2 p = pair[base + i];
        atomicAdd(&cnt[p.x & (BW - 1)], 1);
    }
    __syncthreads();

    int c0 = cnt[2 * t], c1 = cnt[2 * t + 1];
    int s = c0 + c1;
    int lane = t & 63, wid = t >> 6;
    int x = s;
    #pragma unroll
    for (int d = 1; d < 64; d <<= 1) {
        int y = __shfl_up(x, d, 64);
        if (lane >= d) x += y;
    }
    if (lane == 63) wsum[wid] = x;
    __syncthreads();
    if (t == 0) {
        int r = 0;
        for (int w = 0; w < 4; ++w) { woff[w] = r; r += wsum[w]; }
    }
    __syncthreads();
    int ex = woff[wid] + (x - s);
    loff[2 * t] = ex;
    loff[2 * t + 1] = ex + c0;
    __syncthreads();

    int node0 = b << 9;
    for (int i = t; i < BW; i += 256) {
        int node = node0 + i;
        if (node < NN) { deg[node] = cnt[i]; off[node] = base + loff[i]; }
        else if (node == NN) { off[NN] = EE; }
    }
    __syncthreads();

    for (int i = t; i < BW; i += 256) cnt[i] = loff[i];
    __syncthreads();
    for (int i = t; i < m; i += 256) {
        int2 p = pair[base + i];
        int pos = atomicAdd(&cnt[p.x & (BW - 1)], 1);
        if (pos < MAXB) ssrc[pos] = p.y;
        else            csrc[base + pos] = p.y;   // statistically never taken
    }
    __syncthreads();
    int mm = m < MAXB ? m : MAXB;
    for (int i = t; i < mm; i += 256) csrc[base + i] = ssrc[i];   // coalesced
}

__global__ void dinv_k(const int* __restrict__ cnt, float* __restrict__ dinv, int n) {
    int i = blockIdx.x * 256 + threadIdx.x;
    if (i < n) dinv[i] = rsqrtf((float)(cnt[i] + 1));   // +1 self loop
}

// ---------------- fused input-proj weight: Wc = W_in @ conv_W0, bc = b_in @ conv_W0 ----------------
__global__ void wc_k(const float* __restrict__ Win, const float* __restrict__ bin,
                     const float* __restrict__ cw0, float* __restrict__ Wc) {
    int idx = blockIdx.x * 256 + threadIdx.x;
    if (idx < NODE_DIM * HID) {
        int k = idx >> 6, c = idx & 63;
        float a = 0.f;
        #pragma unroll 8
        for (int j = 0; j < HID; ++j) a += Win[k * HID + j] * cw0[j * HID + c];
        Wc[idx] = a;
    } else if (idx < NODE_DIM * HID + HID) {
        int c = idx - NODE_DIM * HID;
        float a = 0.f;
        #pragma unroll 8
        for (int j = 0; j < HID; ++j) a += bin[j] * cw0[j * HID + c];
        Wc[idx] = a;
    }
}

// ---------------- pack W into MFMA B-fragment order (bf16) ----------------
// frag element j of unit u=(s,t,l): W[s*32 + (l>>4)*8 + j][t*16 + (l&15)]
// buffer index = u*8 + j.  WfA: K=128 (1024 units); Wf1/Wf2: K=64 (512 units).
__global__ __launch_bounds__(256) void wfrag_k(const float* __restrict__ Wc,
                                               const float* __restrict__ convW,
                                               short* __restrict__ WfA,
                                               short* __restrict__ Wf1,
                                               short* __restrict__ Wf2) {
    int id = blockIdx.x * 256 + threadIdx.x;   // 0..2047
    const float* W; short* out; int u;
    if (id < 1024)      { W = Wc;           out = WfA; u = id; }
    else if (id < 1536) { W = convW + 4096; out = Wf1; u = id - 1024; }
    else                { W = convW + 8192; out = Wf2; u = id - 1536; }
    int l = u & 63, t = (u >> 6) & 3, s = u >> 8;
    int k0 = s * 32 + ((l >> 4) & 3) * 8;
    int col = t * 16 + (l & 15);
    short8 v;
    #pragma unroll
    for (int j = 0; j < 8; ++j) v[j] = f2bf(W[(k0 + j) * 64 + col]);
    *(short8*)(out + u * 8) = v;
}

// ---------------- MFMA transform: out[n,64] = bf16(in[n,K] @ W[K,64] (+bias)) ----------------
// wave computes a 16x64 tile; W frags held in registers (uniform L2-broadcast
// loads); A streamed from global, no LDS.
template <int K, bool BIAS, bool A_BF16>
__global__ __launch_bounds__(256, 4) void gemm_k(const void* __restrict__ inv,
                                                 const short8* __restrict__ Wf,
                                                 const float* __restrict__ bias,
                                                 __hip_bfloat16* __restrict__ out) {
    constexpr int NS = K / 32;
    int l = threadIdx.x & 63;
    int w = threadIdx.x >> 6;
    int rows0 = blockIdx.x * 64 + w * 16;
    int arow = rows0 + (l & 15);
    bool rok = arow < NN;
    int kgrp = (l >> 4) & 3;

    short8 wf[NS][4];
    #pragma unroll
    for (int s = 0; s < NS; ++s)
        #pragma unroll
        for (int t = 0; t < 4; ++t)
            wf[s][t] = Wf[(s * 4 + t) * 64 + l];

    f32x4 acc[4];
    #pragma unroll
    for (int t = 0; t < 4; ++t) acc[t] = (f32x4){0.f, 0.f, 0.f, 0.f};

    #pragma unroll
    for (int s = 0; s < NS; ++s) {
        short8 af = {0, 0, 0, 0, 0, 0, 0, 0};
        if (A_BF16) {
            if (rok)
                af = *(const short8*)((const short*)inv + (long)arow * K + s * 32 + kgrp * 8);
        } else {
            if (rok) {
                const float* ap = (const float*)inv + (long)arow * K + s * 32 + kgrp * 8;
                float4 a0 = *(const float4*)ap;
                float4 a1 = *(const float4*)(ap + 4);
                af[0] = f2bf(a0.x); af[1] = f2bf(a0.y); af[2] = f2bf(a0.z); af[3] = f2bf(a0.w);
                af[4] = f2bf(a1.x); af[5] = f2bf(a1.y); af[6] = f2bf(a1.z); af[7] = f2bf(a1.w);
            }
        }
        #pragma unroll
        for (int t = 0; t < 4; ++t)
            acc[t] = __builtin_amdgcn_mfma_f32_16x16x32_bf16(af, wf[s][t], acc[t], 0, 0, 0);
    }

    // C/D layout: col = lane&15, row = (lane>>4)*4 + reg  [m89-verified]
    int orow0 = rows0 + kgrp * 4;
    #pragma unroll
    for (int t = 0; t < 4; ++t) {
        int col = t * 16 + (l & 15);
        float b = BIAS ? bias[col] : 0.f;
        #pragma unroll
        for (int r = 0; r < 4; ++r) {
            int row = orow0 + r;
            if (row < NN)
                out[(long)row * HID + col] = __float2bfloat16(acc[t][r] + b);
        }
    }
}

// ---------------- aggregate: out[i] = relu(BN(selfloop + sum_edges + conv_b)) ----------------
__global__ __launch_bounds__(256) void aggregate_k(const __hip_bfloat16* __restrict__ hw,
                                                   const int* __restrict__ off,
                                                   const int* __restrict__ src,
                                                   const float* __restrict__ dinv,
                                                   const float* __restrict__ convb,
                                                   const float* __restrict__ gamma,
                                                   const float* __restrict__ beta,
                                                   const float* __restrict__ mean,
                                                   const float* __restrict__ var,
                                                   __hip_bfloat16* __restrict__ out) {
    int lane = threadIdx.x & 63;
    int i = __builtin_amdgcn_readfirstlane((int)blockIdx.x * 4 + (threadIdx.x >> 6));
    float sc = gamma[lane] * rsqrtf(var[lane] + BN_EPS);
    float sh = (convb[lane] - mean[lane]) * sc + beta[lane];
    float di = dinv[i];
    float acc0 = __bfloat162float(hw[(long)i * HID + lane]) * di * di;  // self loop
    float acc1 = 0.f, acc2 = 0.f, acc3 = 0.f;
    int e0 = off[i], e1 = off[i + 1];
    int e = e0;
    for (; e + 4 <= e1; e += 4) {
        int s0 = src[e], s1 = src[e + 1], s2 = src[e + 2], s3 = src[e + 3];
        float w0 = dinv[s0], w1 = dinv[s1], w2 = dinv[s2], w3 = dinv[s3];
        float h0 = __bfloat162float(hw[(long)s0 * HID + lane]);
        float h1 = __bfloat162float(hw[(long)s1 * HID + lane]);
        float h2 = __bfloat162float(hw[(long)s2 * HID + lane]);
        float h3 = __bfloat162float(hw[(long)s3 * HID + lane]);
        acc0 += h0 * (w0 * di);
        acc1 += h1 * (w1 * di);
        acc2 += h2 * (w2 * di);
        acc3 += h3 * (w3 * di);
    }
    for (; e < e1; ++e) {
        int s = src[e];
        acc0 += __bfloat162float(hw[(long)s * HID + lane]) * (dinv[s] * di);
    }
    float acc = (acc0 + acc1) + (acc2 + acc3);
    float val = fmaxf(acc * sc + sh, 0.f);
    out[(long)i * HID + lane] = __float2bfloat16(val);
}

// ---------------- pooling stage 1: parallel segmented sum over sorted batch ----------------
__global__ __launch_bounds__(256) void pool1_k(const __hip_bfloat16* __restrict__ h,
                                               const int* __restrict__ batch,
                                               float* __restrict__ sums) {
    int lane = threadIdx.x & 63;
    int wid = threadIdx.x >> 6;
    int chunk = blockIdx.x * 4 + wid;
    int i0 = chunk * 64;
    if (i0 >= NN) return;
    int i1 = i0 + 64;
    if (i1 > NN) i1 = NN;
    int g = batch[i0];
    float acc = 0.f;
    for (int i = i0; i < i1; ++i) {
        int bi = batch[i];
        if (bi != g) {
            atomicAdd(&sums[g * HID + lane], acc);
            acc = 0.f;
            g = bi;
        }
        acc += __bfloat162float(h[(long)i * HID + lane]);
    }
    atomicAdd(&sums[g * HID + lane], acc);
}

// ---------------- pooling stage 2 + 3-layer MLP, one block per graph ----------------
__device__ __forceinline__ int lower_bound_i(const int* __restrict__ a, int n, int key) {
    int lo = 0, hi = n;
    while (lo < hi) {
        int m = (lo + hi) >> 1;
        if (a[m] < key) lo = m + 1; else hi = m;
    }
    return lo;
}

__global__ __launch_bounds__(64) void mlp_k(const float* __restrict__ sums,
                                            const int* __restrict__ batch,
                                            const float* __restrict__ W1, const float* __restrict__ b1,
                                            const float* __restrict__ W2, const float* __restrict__ b2,
                                            const float* __restrict__ W3, const float* __restrict__ b3,
                                            float* __restrict__ out) {
    int g = blockIdx.x;
    int lane = threadIdx.x;
    int start = lower_bound_i(batch, NN, g);
    int end = lower_bound_i(batch, NN, g + 1);
    float cnt = (float)(end - start);
    float gv = sums[g * HID + lane] / fmaxf(cnt, 1.0f);

    __shared__ float gs[HID];
    __shared__ float h1s[HID];
    gs[lane] = gv;
    __syncthreads();

    float a1 = b1[lane];
    #pragma unroll 8
    for (int k = 0; k < HID; ++k) a1 += gs[k] * W1[k * HID + lane];
    a1 = fmaxf(a1, 0.f);
    h1s[lane] = a1;
    __syncthreads();

    float a2 = 0.f;
    if (lane < 32) {
        a2 = b2[lane];
        #pragma unroll 8
        for (int k = 0; k < HID; ++k) a2 += h1s[k] * W2[k * 32 + lane];
        a2 = fmaxf(a2, 0.f);
    }
    float p = (lane < 32) ? a2 * W3[lane] : 0.f;
    #pragma unroll
    for (int d = 32; d >= 1; d >>= 1) p += __shfl_down(p, d, 64);
    if (lane == 0) out[g] = p + b3[0];
}

// ---------------- host launch ----------------
extern "C" void kernel_launch(void* const* d_in, const int* in_sizes, int n_in,
                              void* d_out, int out_size, void* d_ws, size_t ws_size,
                              hipStream_t stream) {
    (void)in_sizes; (void)n_in; (void)out_size; (void)ws_size;

    const float* x      = (const float*)d_in[0];
    const int*   eidx   = (const int*)d_in[1];      // [2,E]: src then dst
    const int*   batch  = (const int*)d_in[2];
    const float* W_in   = (const float*)d_in[3];
    const float* b_in   = (const float*)d_in[4];
    const float* conv_W = (const float*)d_in[5];    // [3,64,64]
    const float* conv_b = (const float*)d_in[6];    // [3,64]
    const float* gamma  = (const float*)d_in[7];
    const float* beta   = (const float*)d_in[8];
    const float* mean   = (const float*)d_in[9];
    const float* var    = (const float*)d_in[10];
    const float* W1     = (const float*)d_in[11];
    const float* b1     = (const float*)d_in[12];
    const float* W2     = (const float*)d_in[13];
    const float* b2     = (const float*)d_in[14];
    const float* W3     = (const float*)d_in[15];
    const float* b3     = (const float*)d_in[16];
    float* outp = (float*)d_out;

    int*   wsi = (int*)d_ws;
    float* wsf = (float*)d_ws;

    int*   off    = wsi + I_OFF;
    int*   deg    = wsi + I_DEG;
    int*   hist   = wsi + I_HIST;
    int*   hs     = wsi + I_HS;
    int*   bsums  = wsi + I_BS;
    int*   boffs  = wsi + I_BO;
    int2*  pair   = (int2*)(wsi + I_PAIR);
    int*   csrc   = wsi + I_SRCS;
    float* dinv   = wsf + I_DINV;
    float* Wc     = wsf + I_WC;
    short* WfA    = (short*)(wsi + I_WFA);
    short* Wf1    = (short*)(wsi + I_WF1);
    short* Wf2    = (short*)(wsi + I_WF2);
    __hip_bfloat16* bufA = (__hip_bfloat16*)(wsf + I_BUFA);
    __hip_bfloat16* bufB = (__hip_bfloat16*)(wsf + I_BUFB);
    float* sums   = wsf + I_SUMS;

    const int* esrc = eidx;
    const int* edst = eidx + EE;

    hipMemsetAsync(sums, 0, NGRAPH * HID * sizeof(float), stream);

    // ---- graph prep: two-level counting sort -> deg, off, csrc (coalesced writes)
    hist_k<<<NCHUNK, 256, 0, stream>>>(edst, hist);
    int nb1 = (MHIST + 1023) / 1024;                 // 75
    scan1_k<<<nb1, 256, 0, stream>>>(hist, hs, bsums, MHIST);
    scan2_k<<<1, 128, 0, stream>>>(bsums, boffs, nb1);
    scan3g_k<<<(MHIST + 255) / 256, 256, 0, stream>>>(hs, boffs, MHIST);
    wc_k<<<(NODE_DIM * HID + HID + 255) / 256, 256, 0, stream>>>(W_in, b_in, conv_W, Wc);
    wfrag_k<<<8, 256, 0, stream>>>(Wc, conv_W, WfA, Wf1, Wf2);
    sortB_k<<<NCHUNK, 256, 0, stream>>>(esrc, edst, hs, pair);
    fineC_k<<<NB, 256, 0, stream>>>(pair, hs, deg, off, csrc);
    dinv_k<<<(NN + 255) / 256, 256, 0, stream>>>(deg, dinv, NN);

    int ngemm = (NN + 63) / 64;                 // 1563
    // layer 0: fused input projection + conv transform (A = x, fp32)
    gemm_k<NODE_DIM, true, false><<<ngemm, 256, 0, stream>>>(x, (const short8*)WfA,
                                                             Wc + NODE_DIM * HID, bufA);
    aggregate_k<<<NN / 4, 256, 0, stream>>>(bufA, off, csrc, dinv,
                                            conv_b + 0 * HID, gamma + 0 * HID, beta + 0 * HID,
                                            mean + 0 * HID, var + 0 * HID, bufB);
    // layer 1 (A = bufB, bf16)
    gemm_k<HID, false, true><<<ngemm, 256, 0, stream>>>(bufB, (const short8*)Wf1, nullptr, bufA);
    aggregate_k<<<NN / 4, 256, 0, stream>>>(bufA, off, csrc, dinv,
                                            conv_b + 1 * HID, gamma + 1 * HID, beta + 1 * HID,
                                            mean + 1 * HID, var + 1 * HID, bufB);
    // layer 2
    gemm_k<HID, false, true><<<ngemm, 256, 0, stream>>>(bufB, (const short8*)Wf2, nullptr, bufA);
    aggregate_k<<<NN / 4, 256, 0, stream>>>(bufA, off, csrc, dinv,
                                            conv_b + 2 * HID, gamma + 2 * HID, beta + 2 * HID,
                                            mean + 2 * HID, var + 2 * HID, bufB);

    // mean pool (parallel) + MLP
    pool1_k<<<(NN / 64 + 3) / 4, 256, 0, stream>>>(bufB, batch, sums);
    mlp_k<<<NGRAPH, 64, 0, stream>>>(sums, batch, W1, b1, W2, b2, W3, b3, outp);
}